// Round 6
// baseline (167.203 us; speedup 1.0000x reference)
//
#include <hip/hip_runtime.h>
#include <hip/hip_bf16.h>

#define DIM 128
#define NSUB 8        // XCD-exclusive sub-CSRs (sub = blockIdx.x & 7, round-robin proxy)

#define SCAN_TPB 256
#define SCAN_EPT 4
#define SCAN_CHUNK (SCAN_TPB * SCAN_EPT)   // 1024 elements per scan block

// finish kernel geometry
#define FROWS 64      // M-tile rows per block
#define FPAD 136      // bf16 row stride in LDS: 272B -> 2-way bank alias on b128 (free)

typedef __attribute__((ext_vector_type(8))) short bf16x8;
typedef __attribute__((ext_vector_type(8))) unsigned short u16x8;
typedef __attribute__((ext_vector_type(4))) float f32x4;

__device__ __forceinline__ short f2bf(float f) {
    union { __hip_bfloat16 h; short s; } u;
    u.h = __float2bfloat16(f);   // round-to-nearest-even
    return u.s;
}
__device__ __forceinline__ float bf2f(unsigned short s) {
    union { unsigned int u; float f; } c;
    c.u = ((unsigned int)s) << 16;
    return c.f;
}

// ---------------------------------------------------------------------------
// Detect whether edge_index is int64 or int32 (values < 2^17 => int64 high
// words of first 128 entries are all zero; int32 data there is random).
// ---------------------------------------------------------------------------
__global__ void detect_kernel(const unsigned int* __restrict__ e, int* __restrict__ flags) {
    if (blockIdx.x == 0 && threadIdx.x == 0) {
        int ok64 = 1;
        for (int t = 0; t < 128; ++t) {
            if (e[2 * t + 1] != 0u) { ok64 = 0; break; }
        }
        flags[0] = ok64;
    }
}

__global__ void zero_int_kernel(int* __restrict__ p, int n) {
    int stride = gridDim.x * blockDim.x;
    for (int t = blockIdx.x * blockDim.x + threadIdx.x; t < n; t += stride) p[t] = 0;
}

// x (f32) -> xb (bf16), 8 elems/thread/iter
__global__ __launch_bounds__(256) void cvt_kernel(const float* __restrict__ x,
        unsigned short* __restrict__ xb, int n8) {
    int stride = gridDim.x * blockDim.x;
    for (int t = blockIdx.x * blockDim.x + threadIdx.x; t < n8; t += stride) {
        const float4* p = (const float4*)(x + (size_t)t * 8);
        float4 a = p[0], b = p[1];
        u16x8 o;
        o[0] = (unsigned short)f2bf(a.x); o[1] = (unsigned short)f2bf(a.y);
        o[2] = (unsigned short)f2bf(a.z); o[3] = (unsigned short)f2bf(a.w);
        o[4] = (unsigned short)f2bf(b.x); o[5] = (unsigned short)f2bf(b.y);
        o[6] = (unsigned short)f2bf(b.z); o[7] = (unsigned short)f2bf(b.w);
        *(u16x8*)(xb + (size_t)t * 8) = o;
    }
}

__device__ __forceinline__ int load_dst(const void* eidx, int flag64, int E, int e) {
    return flag64 ? (int)((const long long*)eidx)[E + e] : ((const int*)eidx)[E + e];
}
__device__ __forceinline__ int load_src(const void* eidx, int flag64, int E, int e) {
    return flag64 ? (int)((const long long*)eidx)[e] : ((const int*)eidx)[e];
}

// ---------------------------------------------------------------------------
// CSR build over NSUB XCD-exclusive sub-bins: hist -> scan (sub-major) -> fill
// ---------------------------------------------------------------------------
__global__ void hist_kernel(const void* __restrict__ eidx, int* __restrict__ cnt,
                            const int* __restrict__ flags, int E, int nn) {
    int e = blockIdx.x * blockDim.x + threadIdx.x;
    if (e >= E) return;
    int sub = blockIdx.x & (NSUB - 1);
    atomicAdd(&cnt[sub * nn + load_dst(eidx, flags[0], E, e)], 1);
}

__global__ __launch_bounds__(SCAN_TPB) void scan1_kernel(
        const int* __restrict__ cnt, int* __restrict__ rowstart,
        int* __restrict__ blockSums, int ntot) {
    __shared__ int s[SCAN_TPB];
    const int base = blockIdx.x * SCAN_CHUNK;
    const int tid = threadIdx.x;
    int v[SCAN_EPT];
    int tsum = 0;
    #pragma unroll
    for (int u = 0; u < SCAN_EPT; ++u) {
        int i = base + tid * SCAN_EPT + u;
        int c = (i < ntot) ? cnt[i] : 0;
        v[u] = tsum;
        tsum += c;
    }
    s[tid] = tsum;
    __syncthreads();
    for (int off = 1; off < SCAN_TPB; off <<= 1) {
        int t = (tid >= off) ? s[tid - off] : 0;
        __syncthreads();
        s[tid] += t;
        __syncthreads();
    }
    int ex = s[tid] - tsum;
    #pragma unroll
    for (int u = 0; u < SCAN_EPT; ++u) {
        int i = base + tid * SCAN_EPT + u;
        if (i < ntot) rowstart[i] = ex + v[u];
    }
    if (tid == SCAN_TPB - 1) blockSums[blockIdx.x] = s[tid];
}

__global__ __launch_bounds__(1024) void scan2_kernel(
        const int* __restrict__ blockSums, int* __restrict__ blockOff, int nb) {
    __shared__ int s[1024];
    int tid = threadIdx.x;
    int val = (tid < nb) ? blockSums[tid] : 0;
    s[tid] = val;
    __syncthreads();
    for (int off = 1; off < 1024; off <<= 1) {
        int t = (tid >= off) ? s[tid - off] : 0;
        __syncthreads();
        s[tid] += t;
        __syncthreads();
    }
    if (tid < nb) blockOff[tid] = s[tid] - val;
}

__global__ __launch_bounds__(SCAN_TPB) void scan3_kernel(
        int* __restrict__ rowstart, const int* __restrict__ blockOff, int ntot, int E) {
    const int base = blockIdx.x * SCAN_CHUNK;
    const int off = blockOff[blockIdx.x];
    #pragma unroll
    for (int u = 0; u < SCAN_EPT; ++u) {
        int i = base + threadIdx.x + u * SCAN_TPB;
        if (i < ntot) rowstart[i] += off;
    }
    if (blockIdx.x == 0 && threadIdx.x == 0) rowstart[ntot] = E;
}

// Writes into sub-region (blockIdx&7) come only from blocks on one XCD under
// round-robin dispatch -> no cross-XCD dirty-line sharing -> no 8x write amp.
__global__ void fill_kernel(const void* __restrict__ eidx, const float* __restrict__ ew,
                            const int* __restrict__ rowstart, int* __restrict__ cursor,
                            uint2* __restrict__ srcw, const int* __restrict__ flags,
                            int E, int nn) {
    int e = blockIdx.x * blockDim.x + threadIdx.x;
    if (e >= E) return;
    int sub = blockIdx.x & (NSUB - 1);
    int f = flags[0];
    int src = load_src(eidx, f, E, e);
    int dst = load_dst(eidx, f, E, e);
    int bin = sub * nn + dst;
    int pos = rowstart[bin] + atomicAdd(&cursor[bin], 1);
    uint2 p;
    p.x = (unsigned)src;
    p.y = __float_as_uint(ew[e]);
    srcw[pos] = p;
}

// ---------------------------------------------------------------------------
// Gather: 4 nodes per wave (16 lanes per node, lane owns 8 dims = 16B bf16).
// Node g's edges live in NSUB short segments (sub-major CSR); segments of
// consecutive nodes are adjacent within each sub-region -> 8 parallel
// sequential read streams, L2-friendly. No atomics.
// ---------------------------------------------------------------------------
__global__ __launch_bounds__(256) void gather_kernel(
        const unsigned short* __restrict__ xb, const uint2* __restrict__ srcw,
        const int* __restrict__ rowstart, unsigned short* __restrict__ aggb, int nn) {
    int g = (blockIdx.x * blockDim.x + threadIdx.x) >> 4;   // node
    int sub16 = threadIdx.x & 15;                           // owns dims [8*sub16, +8)
    if (g >= nn) return;
    float acc[8] = {0.f, 0.f, 0.f, 0.f, 0.f, 0.f, 0.f, 0.f};
    int deg = 0;
    #pragma unroll
    for (int sb = 0; sb < NSUB; ++sb) {
        int n0 = rowstart[sb * nn + g];
        int n1 = rowstart[sb * nn + g + 1];   // flattened next segment start
        deg += n1 - n0;
        int e = n0;
        for (; e + 2 <= n1; e += 2) {
            uint2 sw0 = srcw[e];
            uint2 sw1 = srcw[e + 1];
            u16x8 x0 = *(const u16x8*)(xb + (size_t)sw0.x * DIM + sub16 * 8);
            u16x8 x1 = *(const u16x8*)(xb + (size_t)sw1.x * DIM + sub16 * 8);
            float w0 = __uint_as_float(sw0.y);
            float w1 = __uint_as_float(sw1.y);
            #pragma unroll
            for (int j = 0; j < 8; ++j) {
                acc[j] = fmaf(bf2f(x0[j]), w0, acc[j]);
                acc[j] = fmaf(bf2f(x1[j]), w1, acc[j]);
            }
        }
        if (e < n1) {
            uint2 sw = srcw[e];
            u16x8 xr = *(const u16x8*)(xb + (size_t)sw.x * DIM + sub16 * 8);
            float w = __uint_as_float(sw.y);
            #pragma unroll
            for (int j = 0; j < 8; ++j) acc[j] = fmaf(bf2f(xr[j]), w, acc[j]);
        }
    }
    float inv = 1.0f / fmaxf((float)deg, 1.0f);
    u16x8 o;
    #pragma unroll
    for (int j = 0; j < 8; ++j) o[j] = (unsigned short)f2bf(acc[j] * inv);
    *(u16x8*)(aggb + (size_t)g * DIM + sub16 * 8) = o;
}

// ---------------------------------------------------------------------------
// MFMA finish: out = x + alpha*(aggb @ W^T + b). aggb is bf16 in ws; out is
// d_out (overwrites the xb scratch parked there, which is dead by now).
// 512 threads = 8 waves; 64-row M-tile; wave w owns output cols [16w,16w+16).
// C/D map: col=lane&15, row=(lane>>4)*4+reg  [verified, learn_hip m89/m91]
// ---------------------------------------------------------------------------
__global__ __launch_bounds__(512) void finish_kernel(
        const unsigned short* __restrict__ aggb, float* __restrict__ out,
        const float* __restrict__ x, const float* __restrict__ W,
        const float* __restrict__ bias, const float* __restrict__ alphaP, int nn) {
    __shared__ alignas(16) unsigned short A_lds[FROWS * FPAD];   // 17408 B
    const int tid  = threadIdx.x;
    const int wv   = tid >> 6;          // wave 0..7
    const int lane = tid & 63;
    const int half = lane >> 4;         // 0..3 (K-group / row-group)
    const int l16  = lane & 15;         // M-row for A, N-col for B and C/D
    const int b0   = blockIdx.x * FROWS;
    const float alpha = alphaP[0];

    // ---- B-frags: W[jcol][kt*32 + half*8 .. +8] as bf16, loaded once ----
    const int jcol = wv * 16 + l16;
    bf16x8 bfrag[4];
    #pragma unroll
    for (int kt = 0; kt < 4; ++kt) {
        const float4* w4 = (const float4*)(W + (size_t)jcol * DIM + kt * 32 + half * 8);
        float4 lo = w4[0], hi = w4[1];
        bf16x8 b;
        b[0] = f2bf(lo.x); b[1] = f2bf(lo.y); b[2] = f2bf(lo.z); b[3] = f2bf(lo.w);
        b[4] = f2bf(hi.x); b[5] = f2bf(hi.y); b[6] = f2bf(hi.z); b[7] = f2bf(hi.w);
        bfrag[kt] = b;
    }
    const float bias_j = bias[jcol];

    // ---- stage 64 bf16 rows -> LDS: 1024 chunks of 16B, 2 iters ----
    #pragma unroll
    for (int it = 0; it < 2; ++it) {
        int p = it * 512 + tid;          // 0..1023
        int row = p >> 4;                // 0..63
        int c8 = p & 15;                 // 16B chunk within row
        int node = b0 + row;
        u16x8 v = {0, 0, 0, 0, 0, 0, 0, 0};
        if (node < nn) v = *(const u16x8*)(aggb + (size_t)node * DIM + c8 * 8);
        *(u16x8*)&A_lds[row * FPAD + c8 * 8] = v;
    }
    __syncthreads();

    // ---- 4 sub-tiles of 16 rows: MFMA + fused epilogue ----
    #pragma unroll
    for (int mt = 0; mt < 4; ++mt) {
        f32x4 acc = {0.f, 0.f, 0.f, 0.f};
        #pragma unroll
        for (int kt = 0; kt < 4; ++kt) {
            const bf16x8 a = *(const bf16x8*)&A_lds[(mt * 16 + l16) * FPAD + kt * 32 + half * 8];
            acc = __builtin_amdgcn_mfma_f32_16x16x32_bf16(a, bfrag[kt], acc, 0, 0, 0);
        }
        #pragma unroll
        for (int r = 0; r < 4; ++r) {
            int grow = b0 + mt * 16 + half * 4 + r;
            if (grow < nn) {
                size_t idx = (size_t)grow * DIM + jcol;
                out[idx] = x[idx] + alpha * (acc[r] + bias_j);
            }
        }
    }
}

extern "C" void kernel_launch(void* const* d_in, const int* in_sizes, int n_in,
                              void* d_out, int out_size, void* d_ws, size_t ws_size,
                              hipStream_t stream) {
    // inputs: x(0), edge_index(1), num_nodes(2), edge_weight(3), W(4), b(5), alpha(6)
    const float* x      = (const float*)d_in[0];
    const void*  eidx   = d_in[1];
    const float* ew     = (const float*)d_in[3];
    const float* W      = (const float*)d_in[4];
    const float* bias   = (const float*)d_in[5];
    const float* alphaP = (const float*)d_in[6];

    const int NN = in_sizes[0] / DIM;
    const int E  = in_sizes[3];
    const int NTOT = NSUB * NN;     // 800K bins

    // ws layout: aggb u16[NN*DIM] (25.6MB) | srcw uint2[E] (5.1MB)
    //            | cnt int[NTOT] | cursor int[NTOT] | rowstart int[NTOT+1]
    //            | blockSums[1024] | blockOff[1024] | flags[2]   (~41 MB total)
    unsigned short* aggb = (unsigned short*)d_ws;
    uint2* srcw     = (uint2*)(aggb + (size_t)NN * DIM);
    int*   cnt      = (int*)(srcw + E);
    int*   cursor   = cnt + NTOT;
    int*   rowstart = cursor + NTOT;
    int*   blockSums= rowstart + NTOT + 1;
    int*   blockOff = blockSums + 1024;
    int*   flags    = blockOff + 1024;

    // xb (bf16 copy of x) parks in the first half of d_out; dead once finish runs
    unsigned short* xb = (unsigned short*)d_out;
    float* out = (float*)d_out;

    detect_kernel<<<1, 64, 0, stream>>>((const unsigned int*)eidx, flags);

    zero_int_kernel<<<512, 256, 0, stream>>>(cnt, 2 * NTOT);   // cnt + cursor contiguous

    int n8 = NN * DIM / 8;
    cvt_kernel<<<2048, 256, 0, stream>>>(x, xb, n8);

    int eblocks = (E + 255) / 256;
    hist_kernel<<<eblocks, 256, 0, stream>>>(eidx, cnt, flags, E, NN);

    int nscan = (NTOT + SCAN_CHUNK - 1) / SCAN_CHUNK;          // 782 for NN=100K
    scan1_kernel<<<nscan, SCAN_TPB, 0, stream>>>(cnt, rowstart, blockSums, NTOT);
    scan2_kernel<<<1, 1024, 0, stream>>>(blockSums, blockOff, nscan);
    scan3_kernel<<<nscan, SCAN_TPB, 0, stream>>>(rowstart, blockOff, NTOT, E);

    fill_kernel<<<eblocks, 256, 0, stream>>>(eidx, ew, rowstart, cursor, srcw, flags, E, NN);

    int gblocks = (NN + 15) / 16;                              // 16 nodes per 256-thr block
    gather_kernel<<<gblocks, 256, 0, stream>>>(xb, srcw, rowstart, aggb, NN);

    int fblocks = (NN + FROWS - 1) / FROWS;
    finish_kernel<<<fblocks, 512, 0, stream>>>(aggb, out, x, W, bias, alphaP, NN);
}